// Round 2
// baseline (2854.228 us; speedup 1.0000x reference)
//
#include <hip/hip_runtime.h>
#include <cmath>

#define NN 100000
#define NE 3200000
#define C 128
#define NLAYERS 8
#define KGSTRIDE 1040

typedef unsigned int u32;
typedef unsigned short u16;
typedef __attribute__((ext_vector_type(8))) short s16x8;
typedef __attribute__((ext_vector_type(4))) float f32x4;

__device__ __forceinline__ float bf2f(u16 u) { return __uint_as_float(((u32)u) << 16); }
__device__ __forceinline__ u16 f2bf(float f) {
    u32 x = __float_as_uint(f);
    return (u16)((x + 0x7fffu + ((x >> 16) & 1u)) >> 16);  // RNE
}

// ---------------- setup kernels ----------------

__global__ void zero_kernel(int* __restrict__ p, int n) {
    int i = blockIdx.x * blockDim.x + threadIdx.x;
    if (i < n) p[i] = 0;
}

__global__ void count_kernel(const int* __restrict__ col, int* __restrict__ cnt, int n) {
    int e = blockIdx.x * blockDim.x + threadIdx.x;
    if (e < n) atomicAdd(&cnt[col[e]], 1);
}

__global__ void dinv_kernel(const int* __restrict__ cnt, float* __restrict__ dinv, int n) {
    int i = blockIdx.x * blockDim.x + threadIdx.x;
    if (i < n) dinv[i] = rsqrtf((float)(cnt[i] + 1));  // +1 self loop
}

// single-block exclusive scan of cnt -> off (and cursor copy)
__global__ void scan_kernel(const int* __restrict__ cnt, int* __restrict__ off,
                            int* __restrict__ cursor, int n) {
    __shared__ int wsum[16];
    __shared__ int blocktot;
    int tid = threadIdx.x;
    int lane = tid & 63, wid = tid >> 6;
    int carry = 0;
    for (int base = 0; base < n; base += 1024) {
        int i = base + tid;
        int v = (i < n) ? cnt[i] : 0;
        int orig = v;
#pragma unroll
        for (int d = 1; d < 64; d <<= 1) {
            int t = __shfl_up(v, d, 64);
            if (lane >= d) v += t;
        }
        if (lane == 63) wsum[wid] = v;
        __syncthreads();
        if (tid == 0) {
            int run = 0;
#pragma unroll
            for (int w = 0; w < 16; ++w) { int t = wsum[w]; wsum[w] = run; run += t; }
            blocktot = run;
        }
        __syncthreads();
        int excl = v - orig + wsum[wid] + carry;
        if (i < n) { off[i] = excl; cursor[i] = excl; }
        carry += blocktot;
        __syncthreads();
    }
    if (tid == 0) off[n] = carry;
}

__global__ void scatter_kernel(const int* __restrict__ row, const int* __restrict__ col,
                               const float* __restrict__ dinv, int* __restrict__ cursor,
                               int2* __restrict__ csr, int n) {
    int e = blockIdx.x * blockDim.x + threadIdx.x;
    if (e < n) {
        int s = row[e], d = col[e];
        int slot = atomicAdd(&cursor[d], 1);
        int2 pk;
        pk.x = s;
        pk.y = __float_as_int(dinv[s] * dinv[d]);
        csr[slot] = pk;
    }
}

// ---------------- aggregation: one wave per node, bf16 gathers, fp32 out ----

__global__ __launch_bounds__(256) void agg_kernel(
    const u16* __restrict__ hbf, const u16* __restrict__ x0bf,
    const int* __restrict__ off, const int2* __restrict__ csr,
    const float* __restrict__ dinv, float* __restrict__ z) {
    int node = (blockIdx.x * blockDim.x + threadIdx.x) >> 6;
    int lane = threadIdx.x & 63;
    if (node >= NN) return;
    int start = __builtin_amdgcn_readfirstlane(off[node]);
    int end = __builtin_amdgcn_readfirstlane(off[node + 1]);
    float w0 = dinv[node];
    w0 = w0 * w0;  // self-loop weight
    int choff = lane << 1;
    u32 hu = *(const u32*)(hbf + (size_t)node * C + choff);
    float a0 = w0 * bf2f((u16)hu), a1 = w0 * bf2f((u16)(hu >> 16));
    for (int j = start; j < end; ++j) {
        int2 pk = csr[j];
        float w = __int_as_float(pk.y);
        u32 u = *(const u32*)(hbf + (size_t)pk.x * C + choff);
        a0 = fmaf(w, bf2f((u16)u), a0);
        a1 = fmaf(w, bf2f((u16)(u >> 16)), a1);
    }
    u32 xu = *(const u32*)(x0bf + (size_t)node * C + choff);
    float z0 = 0.9f * a0 + 0.1f * bf2f((u16)xu);
    float z1 = 0.9f * a1 + 0.1f * bf2f((u16)(xu >> 16));
    *(float2*)(z + (size_t)node * C + choff) = make_float2(z0, z1);
}

// ---------------- GEMM (MFMA 16x16x32 bf16, hi/lo split for fp32 accuracy) --
// W (k,n) fp32 row-major staged to LDS as Whi/Wlo[kgroup][n][8], kgroup
// stride 1040 u16 (2080 B) to spread b128 reads over bank residues.

__device__ __forceinline__ void stage_w32(const float* __restrict__ W, u16* Whi, u16* Wlo) {
    int tid = threadIdx.x;
    for (int base = tid * 8; base < C * C; base += 256 * 8) {
        int k = base >> 7, n0 = base & 127;
        int kg = k >> 3, kr = k & 7;
#pragma unroll
        for (int j = 0; j < 8; ++j) {
            float v = W[base + j];
            u16 hi = f2bf(v);
            float lo = v - bf2f(hi);
            Whi[kg * KGSTRIDE + (n0 + j) * 8 + kr] = hi;
            Wlo[kg * KGSTRIDE + (n0 + j) * 8 + kr] = f2bf(lo);
        }
    }
}

__device__ __forceinline__ void build_a(const float* __restrict__ p, s16x8& hi, s16x8& lo) {
#pragma unroll
    for (int j = 0; j < 8; ++j) {
        float v = p[j];
        u16 h = f2bf(v);
        hi[j] = (short)h;
        lo[j] = (short)f2bf(v - bf2f(h));
    }
}

__global__ __launch_bounds__(256) void gemm_proj(
    const float* __restrict__ X, const float* __restrict__ Wp, const float* __restrict__ bias,
    u16* __restrict__ x0bf, float* __restrict__ h32, u16* __restrict__ hbf) {
    __shared__ u16 Wt[2 * 16 * KGSTRIDE];
    u16* Whi = Wt;
    u16* Wlo = Wt + 16 * KGSTRIDE;
    stage_w32(Wp, Whi, Wlo);
    __syncthreads();
    int tid = threadIdx.x;
    int wave = tid >> 6, lane = tid & 63;
    int quad = lane >> 4, l16 = lane & 15;
    int rowbase = blockIdx.x * 64 + wave * 16;
    int arow = rowbase + l16;
    if (arow >= NN) arow = NN - 1;
    const float* aptr = X + (size_t)arow * C + quad * 8;
    s16x8 ahi[4], alo[4];
#pragma unroll
    for (int c2 = 0; c2 < 4; ++c2) build_a(aptr + c2 * 32, ahi[c2], alo[c2]);
    f32x4 acc[8];
#pragma unroll
    for (int t = 0; t < 8; ++t) acc[t] = f32x4{0.f, 0.f, 0.f, 0.f};
#pragma unroll
    for (int c2 = 0; c2 < 4; ++c2) {
#pragma unroll
        for (int t = 0; t < 8; ++t) {
            const u16* bp = &Whi[(c2 * 4 + quad) * KGSTRIDE + (t * 16 + l16) * 8];
            s16x8 bh = *(const s16x8*)bp;
            s16x8 bl = *(const s16x8*)(bp + 16 * KGSTRIDE);
            acc[t] = __builtin_amdgcn_mfma_f32_16x16x32_bf16(ahi[c2], bh, acc[t], 0, 0, 0);
            acc[t] = __builtin_amdgcn_mfma_f32_16x16x32_bf16(alo[c2], bh, acc[t], 0, 0, 0);
            acc[t] = __builtin_amdgcn_mfma_f32_16x16x32_bf16(ahi[c2], bl, acc[t], 0, 0, 0);
        }
    }
#pragma unroll
    for (int t = 0; t < 8; ++t) {
        int n = t * 16 + l16;
        float bv = bias[n];
#pragma unroll
        for (int r = 0; r < 4; ++r) {
            int m = rowbase + quad * 4 + r;
            if (m < NN) {
                float v = acc[t][r] + bv;
                size_t idx = (size_t)m * C + n;
                h32[idx] = v;
                u16 b16 = f2bf(v);
                x0bf[idx] = b16;
                hbf[idx] = b16;
            }
        }
    }
}

__global__ __launch_bounds__(256) void gemm_layer(
    const float* __restrict__ Z, const float* __restrict__ W,
    const float* __restrict__ h32, float* __restrict__ out32,
    u16* __restrict__ houtbf, float beta, int relu) {
    __shared__ u16 Wt[2 * 16 * KGSTRIDE];
    u16* Whi = Wt;
    u16* Wlo = Wt + 16 * KGSTRIDE;
    stage_w32(W, Whi, Wlo);
    __syncthreads();
    int tid = threadIdx.x;
    int wave = tid >> 6, lane = tid & 63;
    int quad = lane >> 4, l16 = lane & 15;
    int rowbase = blockIdx.x * 64 + wave * 16;
    int arow = rowbase + l16;
    if (arow >= NN) arow = NN - 1;
    const float* aptr = Z + (size_t)arow * C + quad * 8;
    s16x8 ahi[4], alo[4];
#pragma unroll
    for (int c2 = 0; c2 < 4; ++c2) build_a(aptr + c2 * 32, ahi[c2], alo[c2]);
    f32x4 acc[8];
#pragma unroll
    for (int t = 0; t < 8; ++t) acc[t] = f32x4{0.f, 0.f, 0.f, 0.f};
#pragma unroll
    for (int c2 = 0; c2 < 4; ++c2) {
#pragma unroll
        for (int t = 0; t < 8; ++t) {
            const u16* bp = &Whi[(c2 * 4 + quad) * KGSTRIDE + (t * 16 + l16) * 8];
            s16x8 bh = *(const s16x8*)bp;
            s16x8 bl = *(const s16x8*)(bp + 16 * KGSTRIDE);
            acc[t] = __builtin_amdgcn_mfma_f32_16x16x32_bf16(ahi[c2], bh, acc[t], 0, 0, 0);
            acc[t] = __builtin_amdgcn_mfma_f32_16x16x32_bf16(alo[c2], bh, acc[t], 0, 0, 0);
            acc[t] = __builtin_amdgcn_mfma_f32_16x16x32_bf16(ahi[c2], bl, acc[t], 0, 0, 0);
        }
    }
    float omb = 1.0f - beta;
#pragma unroll
    for (int t = 0; t < 8; ++t) {
        int n = t * 16 + l16;
#pragma unroll
        for (int r = 0; r < 4; ++r) {
            int m = rowbase + quad * 4 + r;
            if (m < NN) {
                size_t idx = (size_t)m * C + n;
                float zv = Z[idx];
                float raw = omb * zv + beta * acc[t][r];
                float hn = raw + h32[idx];
                if (relu) hn = fmaxf(hn, 0.f);
                out32[idx] = hn;
                houtbf[idx] = f2bf(hn);
            }
        }
    }
}

// ---------------- host ----------------

extern "C" void kernel_launch(void* const* d_in, const int* in_sizes, int n_in,
                              void* d_out, int out_size, void* d_ws, size_t ws_size,
                              hipStream_t stream) {
    const float* x = (const float*)d_in[0];
    const int* ei = (const int*)d_in[1];
    const float* Wp = (const float*)d_in[2];
    const float* bp = (const float*)d_in[3];
    const float* cw = (const float*)d_in[4];
    const int* row = ei;
    const int* col = ei + NE;

    char* ws = (char*)d_ws;
    size_t o = 0;
    auto alloc = [&](size_t bytes) {
        void* p = ws + o;
        o += (bytes + 255) & ~(size_t)255;
        return p;
    };
    int* off = (int*)alloc((NN + 1) * 4);
    int* cursor = (int*)alloc(NN * 4);
    int* cnt = (int*)alloc(NN * 4);
    float* dinv = (float*)alloc(NN * 4);
    int2* csr = (int2*)alloc((size_t)NE * 8);
    u16* x0bf = (u16*)alloc((size_t)NN * C * 2);
    u16* hbf = (u16*)alloc((size_t)NN * C * 2);
    float* z = (float*)alloc((size_t)NN * C * 4);
    float* h32 = (float*)alloc((size_t)NN * C * 4);

    zero_kernel<<<(NN + 255) / 256, 256, 0, stream>>>(cnt, NN);
    count_kernel<<<(NE + 255) / 256, 256, 0, stream>>>(col, cnt, NE);
    dinv_kernel<<<(NN + 255) / 256, 256, 0, stream>>>(cnt, dinv, NN);
    scan_kernel<<<1, 1024, 0, stream>>>(cnt, off, cursor, NN);
    scatter_kernel<<<(NE + 255) / 256, 256, 0, stream>>>(row, col, dinv, cursor, csr, NE);
    gemm_proj<<<(NN + 63) / 64, 256, 0, stream>>>(x, Wp, bp, x0bf, h32, hbf);

    for (int l = 0; l < NLAYERS; ++l) {
        float beta = logf(0.5f / (float)(l + 1) + 1.0f);
        agg_kernel<<<NN / 4, 256, 0, stream>>>(hbf, x0bf, off, csr, dinv, z);
        float* out32 = (l == NLAYERS - 1) ? (float*)d_out : h32;
        gemm_layer<<<(NN + 63) / 64, 256, 0, stream>>>(z, cw + (size_t)l * C * C, h32, out32,
                                                       hbf, beta, (l < NLAYERS - 1) ? 1 : 0);
    }
}

// Round 3
// 2162.090 us; speedup vs baseline: 1.3201x; 1.3201x over previous
//
#include <hip/hip_runtime.h>
#include <cmath>

#define NN 100000
#define NE 3200000
#define C 128
#define NLAYERS 8

typedef unsigned int u32;
typedef unsigned short u16;
typedef __attribute__((ext_vector_type(8))) short s16x8;
typedef __attribute__((ext_vector_type(4))) float f32x4;

__device__ __forceinline__ float bf2f(u16 u) { return __uint_as_float(((u32)u) << 16); }
__device__ __forceinline__ u16 f2bf(float f) {
    u32 x = __float_as_uint(f);
    return (u16)((x + 0x7fffu + ((x >> 16) & 1u)) >> 16);  // RNE
}

// ---------------- setup kernels ----------------

__global__ void zero_kernel(int* __restrict__ p, int n) {
    int i = blockIdx.x * blockDim.x + threadIdx.x;
    if (i < n) p[i] = 0;
}

__global__ void count_kernel(const int* __restrict__ col, int* __restrict__ cnt, int n) {
    int e = blockIdx.x * blockDim.x + threadIdx.x;
    if (e < n) atomicAdd(&cnt[col[e]], 1);
}

__global__ void dinv_kernel(const int* __restrict__ cnt, float* __restrict__ dinv, int n) {
    int i = blockIdx.x * blockDim.x + threadIdx.x;
    if (i < n) dinv[i] = rsqrtf((float)(cnt[i] + 1));  // +1 self loop
}

// single-block exclusive scan of cnt -> off (and cursor copy)
__global__ void scan_kernel(const int* __restrict__ cnt, int* __restrict__ off,
                            int* __restrict__ cursor, int n) {
    __shared__ int wsum[16];
    __shared__ int blocktot;
    int tid = threadIdx.x;
    int lane = tid & 63, wid = tid >> 6;
    int carry = 0;
    for (int base = 0; base < n; base += 1024) {
        int i = base + tid;
        int v = (i < n) ? cnt[i] : 0;
        int orig = v;
#pragma unroll
        for (int d = 1; d < 64; d <<= 1) {
            int t = __shfl_up(v, d, 64);
            if (lane >= d) v += t;
        }
        if (lane == 63) wsum[wid] = v;
        __syncthreads();
        if (tid == 0) {
            int run = 0;
#pragma unroll
            for (int w = 0; w < 16; ++w) { int t = wsum[w]; wsum[w] = run; run += t; }
            blocktot = run;
        }
        __syncthreads();
        int excl = v - orig + wsum[wid] + carry;
        if (i < n) { off[i] = excl; cursor[i] = excl; }
        carry += blocktot;
        __syncthreads();
    }
    if (tid == 0) off[n] = carry;
}

__global__ void scatter_kernel(const int* __restrict__ row, const int* __restrict__ col,
                               const float* __restrict__ dinv, int* __restrict__ cursor,
                               int2* __restrict__ csr, int n) {
    int e = blockIdx.x * blockDim.x + threadIdx.x;
    if (e < n) {
        int s = row[e], d = col[e];
        int slot = atomicAdd(&cursor[d], 1);
        int2 pk;
        pk.x = s;
        pk.y = __float_as_int(dinv[s] * dinv[d]);
        csr[slot] = pk;
    }
}

// Convert proj weight + 8 layer weights (fp32, (k,n) row-major) to bf16
// hi/lo in B-fragment layout Wb[mat][n*128+k]. 9*16K elements, one thread ea.
__global__ void prep_w(const float* __restrict__ Wp, const float* __restrict__ cw,
                       u16* __restrict__ Wbh, u16* __restrict__ Wbl) {
    int tid = blockIdx.x * blockDim.x + threadIdx.x;
    if (tid >= 9 * C * C) return;
    int mat = tid >> 14;
    int r = tid & 16383;
    int n = r >> 7, k = r & 127;  // k fastest -> coalesced writes
    float v = (mat == 0) ? Wp[k * C + n] : cw[(size_t)(mat - 1) * C * C + k * C + n];
    u16 hi = f2bf(v);
    float lo = v - bf2f(hi);
    Wbh[tid] = hi;
    Wbl[tid] = f2bf(lo);
}

// ---------------- aggregation: one wave per node, 4-deep MLP unroll --------

__global__ __launch_bounds__(256) void agg_kernel(
    const u16* __restrict__ hbf, const u16* __restrict__ x0bf,
    const int* __restrict__ off, const int2* __restrict__ csr,
    const float* __restrict__ dinv, float* __restrict__ z) {
    int node = (blockIdx.x * blockDim.x + threadIdx.x) >> 6;
    int lane = threadIdx.x & 63;
    if (node >= NN) return;
    int start = __builtin_amdgcn_readfirstlane(off[node]);
    int end = __builtin_amdgcn_readfirstlane(off[node + 1]);
    float w0 = dinv[node];
    w0 = w0 * w0;  // self-loop weight
    const u16* hb = hbf + (lane << 1);
    u32 hu = *(const u32*)(hb + (size_t)node * C);
    float a0 = w0 * bf2f((u16)hu), a1 = w0 * bf2f((u16)(hu >> 16));
    float b0 = 0.f, b1 = 0.f, c0 = 0.f, c1 = 0.f, d0 = 0.f, d1 = 0.f;
    int j = start;
    for (; j + 4 <= end; j += 4) {
        int2 p0 = csr[j], p1 = csr[j + 1], p2 = csr[j + 2], p3 = csr[j + 3];
        u32 u0 = *(const u32*)(hb + (size_t)p0.x * C);
        u32 u1 = *(const u32*)(hb + (size_t)p1.x * C);
        u32 u2 = *(const u32*)(hb + (size_t)p2.x * C);
        u32 u3 = *(const u32*)(hb + (size_t)p3.x * C);
        float w_0 = __int_as_float(p0.y), w_1 = __int_as_float(p1.y);
        float w_2 = __int_as_float(p2.y), w_3 = __int_as_float(p3.y);
        a0 = fmaf(w_0, bf2f((u16)u0), a0); a1 = fmaf(w_0, bf2f((u16)(u0 >> 16)), a1);
        b0 = fmaf(w_1, bf2f((u16)u1), b0); b1 = fmaf(w_1, bf2f((u16)(u1 >> 16)), b1);
        c0 = fmaf(w_2, bf2f((u16)u2), c0); c1 = fmaf(w_2, bf2f((u16)(u2 >> 16)), c1);
        d0 = fmaf(w_3, bf2f((u16)u3), d0); d1 = fmaf(w_3, bf2f((u16)(u3 >> 16)), d1);
    }
    for (; j < end; ++j) {
        int2 pk = csr[j];
        float w = __int_as_float(pk.y);
        u32 u = *(const u32*)(hb + (size_t)pk.x * C);
        a0 = fmaf(w, bf2f((u16)u), a0);
        a1 = fmaf(w, bf2f((u16)(u >> 16)), a1);
    }
    a0 += (b0 + c0) + d0;
    a1 += (b1 + c1) + d1;
    u32 xu = *(const u32*)(x0bf + (size_t)node * C + (lane << 1));
    float z0 = 0.9f * a0 + 0.1f * bf2f((u16)xu);
    float z1 = 0.9f * a1 + 0.1f * bf2f((u16)(xu >> 16));
    *(float2*)(z + (size_t)node * C + (lane << 1)) = make_float2(z0, z1);
}

// ---------------- GEMM (MFMA 16x16x32 bf16, hi/lo split, no LDS) -----------
// B-fragments loaded straight from prepped Wb[n*128+k] (L1/L2-resident).

__device__ __forceinline__ void build_a(const float* __restrict__ p, s16x8& hi, s16x8& lo) {
#pragma unroll
    for (int j = 0; j < 8; ++j) {
        float v = p[j];
        u16 h = f2bf(v);
        hi[j] = (short)h;
        lo[j] = (short)f2bf(v - bf2f(h));
    }
}

__global__ __launch_bounds__(256) void gemm_proj(
    const float* __restrict__ X, const u16* __restrict__ Wbh, const u16* __restrict__ Wbl,
    const float* __restrict__ bias,
    u16* __restrict__ x0bf, float* __restrict__ h32, u16* __restrict__ hbf) {
    int tid = threadIdx.x;
    int wave = tid >> 6, lane = tid & 63;
    int quad = lane >> 4, l16 = lane & 15;
    int rowbase = blockIdx.x * 64 + wave * 16;
    int arow = rowbase + l16;
    if (arow >= NN) arow = NN - 1;
    const float* aptr = X + (size_t)arow * C + quad * 8;
    s16x8 ahi[4], alo[4];
#pragma unroll
    for (int c2 = 0; c2 < 4; ++c2) build_a(aptr + c2 * 32, ahi[c2], alo[c2]);
    f32x4 acc[8];
#pragma unroll
    for (int t = 0; t < 8; ++t) acc[t] = f32x4{0.f, 0.f, 0.f, 0.f};
#pragma unroll
    for (int c2 = 0; c2 < 4; ++c2) {
#pragma unroll
        for (int t = 0; t < 8; ++t) {
            int widx = (t * 16 + l16) * C + c2 * 32 + quad * 8;
            s16x8 bh = *(const s16x8*)(Wbh + widx);
            s16x8 bl = *(const s16x8*)(Wbl + widx);
            acc[t] = __builtin_amdgcn_mfma_f32_16x16x32_bf16(ahi[c2], bh, acc[t], 0, 0, 0);
            acc[t] = __builtin_amdgcn_mfma_f32_16x16x32_bf16(alo[c2], bh, acc[t], 0, 0, 0);
            acc[t] = __builtin_amdgcn_mfma_f32_16x16x32_bf16(ahi[c2], bl, acc[t], 0, 0, 0);
        }
    }
#pragma unroll
    for (int t = 0; t < 8; ++t) {
        int n = t * 16 + l16;
        float bv = bias[n];
#pragma unroll
        for (int r = 0; r < 4; ++r) {
            int m = rowbase + quad * 4 + r;
            if (m < NN) {
                float v = acc[t][r] + bv;
                size_t idx = (size_t)m * C + n;
                h32[idx] = v;
                u16 b16 = f2bf(v);
                x0bf[idx] = b16;
                hbf[idx] = b16;
            }
        }
    }
}

__global__ __launch_bounds__(256) void gemm_layer(
    const float* __restrict__ Z, const u16* __restrict__ Wbh, const u16* __restrict__ Wbl,
    const float* __restrict__ h32, float* __restrict__ out32,
    u16* __restrict__ houtbf, float beta, int relu) {
    int tid = threadIdx.x;
    int wave = tid >> 6, lane = tid & 63;
    int quad = lane >> 4, l16 = lane & 15;
    int rowbase = blockIdx.x * 64 + wave * 16;
    int arow = rowbase + l16;
    if (arow >= NN) arow = NN - 1;
    const float* aptr = Z + (size_t)arow * C + quad * 8;
    s16x8 ahi[4], alo[4];
#pragma unroll
    for (int c2 = 0; c2 < 4; ++c2) build_a(aptr + c2 * 32, ahi[c2], alo[c2]);
    f32x4 acc[8];
#pragma unroll
    for (int t = 0; t < 8; ++t) acc[t] = f32x4{0.f, 0.f, 0.f, 0.f};
#pragma unroll
    for (int c2 = 0; c2 < 4; ++c2) {
#pragma unroll
        for (int t = 0; t < 8; ++t) {
            int widx = (t * 16 + l16) * C + c2 * 32 + quad * 8;
            s16x8 bh = *(const s16x8*)(Wbh + widx);
            s16x8 bl = *(const s16x8*)(Wbl + widx);
            acc[t] = __builtin_amdgcn_mfma_f32_16x16x32_bf16(ahi[c2], bh, acc[t], 0, 0, 0);
            acc[t] = __builtin_amdgcn_mfma_f32_16x16x32_bf16(alo[c2], bh, acc[t], 0, 0, 0);
            acc[t] = __builtin_amdgcn_mfma_f32_16x16x32_bf16(ahi[c2], bl, acc[t], 0, 0, 0);
        }
    }
    float omb = 1.0f - beta;
#pragma unroll
    for (int t = 0; t < 8; ++t) {
        int n = t * 16 + l16;
#pragma unroll
        for (int r = 0; r < 4; ++r) {
            int m = rowbase + quad * 4 + r;
            if (m < NN) {
                size_t idx = (size_t)m * C + n;
                float zv = Z[idx];
                float raw = omb * zv + beta * acc[t][r];
                float hn = raw + h32[idx];
                if (relu) hn = fmaxf(hn, 0.f);
                out32[idx] = hn;
                houtbf[idx] = f2bf(hn);
            }
        }
    }
}

// ---------------- host ----------------

extern "C" void kernel_launch(void* const* d_in, const int* in_sizes, int n_in,
                              void* d_out, int out_size, void* d_ws, size_t ws_size,
                              hipStream_t stream) {
    const float* x = (const float*)d_in[0];
    const int* ei = (const int*)d_in[1];
    const float* Wp = (const float*)d_in[2];
    const float* bp = (const float*)d_in[3];
    const float* cw = (const float*)d_in[4];
    const int* row = ei;
    const int* col = ei + NE;

    char* ws = (char*)d_ws;
    size_t o = 0;
    auto alloc = [&](size_t bytes) {
        void* p = ws + o;
        o += (bytes + 255) & ~(size_t)255;
        return p;
    };
    int* off = (int*)alloc((NN + 1) * 4);
    int* cursor = (int*)alloc(NN * 4);
    int* cnt = (int*)alloc(NN * 4);
    float* dinv = (float*)alloc(NN * 4);
    int2* csr = (int2*)alloc((size_t)NE * 8);
    u16* x0bf = (u16*)alloc((size_t)NN * C * 2);
    u16* hbf = (u16*)alloc((size_t)NN * C * 2);
    float* z = (float*)alloc((size_t)NN * C * 4);
    float* h32 = (float*)alloc((size_t)NN * C * 4);
    u16* Wbh = (u16*)alloc((size_t)9 * C * C * 2);
    u16* Wbl = (u16*)alloc((size_t)9 * C * C * 2);

    zero_kernel<<<(NN + 255) / 256, 256, 0, stream>>>(cnt, NN);
    count_kernel<<<(NE + 255) / 256, 256, 0, stream>>>(col, cnt, NE);
    dinv_kernel<<<(NN + 255) / 256, 256, 0, stream>>>(cnt, dinv, NN);
    scan_kernel<<<1, 1024, 0, stream>>>(cnt, off, cursor, NN);
    scatter_kernel<<<(NE + 255) / 256, 256, 0, stream>>>(row, col, dinv, cursor, csr, NE);
    prep_w<<<(9 * C * C + 255) / 256, 256, 0, stream>>>(Wp, cw, Wbh, Wbl);
    gemm_proj<<<(NN + 63) / 64, 256, 0, stream>>>(x, Wbh, Wbl, bp, x0bf, h32, hbf);

    for (int l = 0; l < NLAYERS; ++l) {
        float beta = logf(0.5f / (float)(l + 1) + 1.0f);
        agg_kernel<<<NN / 4, 256, 0, stream>>>(hbf, x0bf, off, csr, dinv, z);
        float* out32 = (l == NLAYERS - 1) ? (float*)d_out : h32;
        gemm_layer<<<(NN + 63) / 64, 256, 0, stream>>>(
            z, Wbh + (size_t)(l + 1) * C * C, Wbl + (size_t)(l + 1) * C * C,
            h32, out32, hbf, beta, (l < NLAYERS - 1) ? 1 : 0);
    }
}